// Round 1
// baseline (979.317 us; speedup 1.0000x reference)
//
#include <hip/hip_runtime.h>
#include <cstdint>

typedef unsigned short u16;
typedef __attribute__((ext_vector_type(8))) short bf16x8;
typedef __attribute__((ext_vector_type(4))) float f32x4;

__device__ __forceinline__ u16 f2b(float f) {
  union { float f; unsigned u; } c; c.f = f;
  unsigned u = c.u;
  return (u16)((u + 0x7FFFu + ((u >> 16) & 1u)) >> 16);
}
__device__ __forceinline__ float b2f(u16 b) {
  union { unsigned u; float f; } c; c.u = ((unsigned)b) << 16;
  return c.f;
}

typedef __attribute__((address_space(1))) void gv_t;
typedef __attribute__((address_space(3))) void lv_t;
__device__ __forceinline__ void gload_lds16(const void* g, void* l) {
  __builtin_amdgcn_global_load_lds((gv_t*)g, (lv_t*)l, 16, 0, 0);
}

// ---------------------------------------------------------------------------
// Transpose + fp32->bf16 convert: out[c][r] = bf16(in[r][c]); in is R x C.
// block (32,8), grid (C/32, R/32)
// ---------------------------------------------------------------------------
__global__ void transpose_f2b(const float* __restrict__ in, u16* __restrict__ out,
                              int R, int C) {
  __shared__ float t[32][33];
  const int c0 = blockIdx.x * 32, r0 = blockIdx.y * 32;
  const int tx = threadIdx.x, ty = threadIdx.y;
#pragma unroll
  for (int i = 0; i < 4; ++i)
    t[ty + 8 * i][tx] = in[(size_t)(r0 + ty + 8 * i) * C + c0 + tx];
  __syncthreads();
#pragma unroll
  for (int i = 0; i < 4; ++i)
    out[(size_t)(c0 + ty + 8 * i) * R + r0 + tx] = f2b(t[tx][ty + 8 * i]);
}

// ---------------------------------------------------------------------------
// RMSNorm: one row (1024 fp32) per block of 256 threads; bf16 out.
// ---------------------------------------------------------------------------
__global__ __launch_bounds__(256) void rmsnorm_k(const float* __restrict__ x,
                                                 const float* __restrict__ g,
                                                 u16* __restrict__ out) {
  const int row = blockIdx.x, tid = threadIdx.x;
  const float4 v = ((const float4*)x)[(size_t)row * 256 + tid];
  float ss = v.x * v.x + v.y * v.y + v.z * v.z + v.w * v.w;
#pragma unroll
  for (int off = 1; off < 64; off <<= 1) ss += __shfl_xor(ss, off, 64);
  __shared__ float red[4];
  if ((tid & 63) == 0) red[tid >> 6] = ss;
  __syncthreads();
  const float mean = (red[0] + red[1] + red[2] + red[3]) * (1.0f / 1024.0f);
  const float rinv = 1.0f / sqrtf(mean + 1e-6f);
  const float4 gv = ((const float4*)g)[tid];
  u16* o = out + (size_t)row * 1024 + tid * 4;
  o[0] = f2b(v.x * rinv * gv.x);
  o[1] = f2b(v.y * rinv * gv.y);
  o[2] = f2b(v.z * rinv * gv.z);
  o[3] = f2b(v.w * rinv * gv.w);
}

// ---------------------------------------------------------------------------
// RoPE in-place on bf16 (B,T,NH,HD) with HD=64, T=2048, NH=16.
// One thread per (b,t,h,d) pair, d in [0,32).
// ---------------------------------------------------------------------------
__global__ __launch_bounds__(256) void rope_k(u16* __restrict__ q) {
  const int i = blockIdx.x * 256 + threadIdx.x;
  const int d = i & 31;
  const int bt = i >> 9;            // b*T + t
  const int t = bt & 2047;          // T = 2048
  // inv_freq = 10000^(-d/32) = exp(-d * ln(10000)/32)
  const float inv = expf((float)d * -0.28782313662425572f);
  const float th = (float)t * inv;
  float s, c;
  sincosf(th, &s, &c);
  const size_t base = (size_t)(i >> 5) * 64;   // ((b*T+t)*NH + h) * HD
  const float x1 = b2f(q[base + d]);
  const float x2 = b2f(q[base + d + 32]);
  q[base + d]      = f2b(x1 * c - x2 * s);
  q[base + d + 32] = f2b(x2 * c + x1 * s);
}

// ---------------------------------------------------------------------------
// GEMM: C[M,N] = A[M,K] @ B[K,N] with BT = B^T given as (N,K) row-major bf16.
// m97 structure: 128x128 tile, BK=32, 256 thr (4 waves, 2x2 of 64x64),
// global_load_lds width=16 staging, mfma_f32_16x16x32_bf16.
// EPI 0: bf16 store.  EPI 1: fp32 store of resid[off] + acc.
// ---------------------------------------------------------------------------
template <int EPI>
__global__ __launch_bounds__(256)
void gemm_bt(const u16* __restrict__ A, const u16* __restrict__ BT,
             void* __restrict__ Cout, const float* __restrict__ resid,
             int M, int N, int K) {
  __shared__ alignas(16) u16 As[128 * 32];
  __shared__ alignas(16) u16 Bs[128 * 32];
  const int tid = threadIdx.x;
  const int wave = tid >> 6, lane = tid & 63;
  const int wr = wave >> 1, wc = wave & 1;
  const int l15 = lane & 15, quad = lane >> 4;
  const int bm = blockIdx.x * 128, bn = blockIdx.y * 128;

  f32x4 acc[4][4];
#pragma unroll
  for (int i = 0; i < 4; ++i)
#pragma unroll
    for (int j = 0; j < 4; ++j) acc[i][j] = (f32x4){0.f, 0.f, 0.f, 0.f};

  // staging: wave w covers tile rows [32w, 32w+32); 2 insts x 16 rows each.
  const int srow = wave * 32 + (lane >> 2);
  const int scol = (lane & 3) * 8;
  const u16* gA0 = A + (size_t)(bm + srow) * K + scol;
  const u16* gA1 = gA0 + (size_t)16 * K;
  const u16* gB0 = BT + (size_t)(bn + srow) * K + scol;
  const u16* gB1 = gB0 + (size_t)16 * K;
  u16* lA0 = As + wave * 1024; u16* lA1 = lA0 + 512;
  u16* lB0 = Bs + wave * 1024; u16* lB1 = lB0 + 512;

  const u16* pa = As + (wr * 64 + l15) * 32 + quad * 8;
  const u16* pb = Bs + (wc * 64 + l15) * 32 + quad * 8;

  for (int kt = 0; kt < K; kt += 32) {
    gload_lds16(gA0 + kt, lA0);
    gload_lds16(gA1 + kt, lA1);
    gload_lds16(gB0 + kt, lB0);
    gload_lds16(gB1 + kt, lB1);
    __syncthreads();
    bf16x8 af[4], bfv[4];
#pragma unroll
    for (int i = 0; i < 4; ++i) af[i] = *(const bf16x8*)(pa + i * 512);
#pragma unroll
    for (int j = 0; j < 4; ++j) bfv[j] = *(const bf16x8*)(pb + j * 512);
#pragma unroll
    for (int i = 0; i < 4; ++i)
#pragma unroll
      for (int j = 0; j < 4; ++j)
        acc[i][j] = __builtin_amdgcn_mfma_f32_16x16x32_bf16(af[i], bfv[j], acc[i][j], 0, 0, 0);
    __syncthreads();
  }

#pragma unroll
  for (int i = 0; i < 4; ++i) {
    const int gr = bm + wr * 64 + i * 16 + quad * 4;
#pragma unroll
    for (int j = 0; j < 4; ++j) {
      const int gc = bn + wc * 64 + j * 16 + l15;
#pragma unroll
      for (int r = 0; r < 4; ++r) {
        const size_t off = (size_t)(gr + r) * N + gc;
        if (EPI == 0) {
          ((u16*)Cout)[off] = f2b(acc[i][j][r]);
        } else {
          ((float*)Cout)[off] = resid[off] + acc[i][j][r];
        }
      }
    }
  }
}

// ---------------------------------------------------------------------------
// Causal flash attention. Q,K,V,O: (B,T,NH,HD) bf16, HD=64, scale=1/8.
// Block = 256 thr = 4 waves; block handles (b,h, 64 q rows); wave owns 16 rows.
// Key tiles of 32. QK^T + PV via mfma 16x16x32; P via per-wave LDS roundtrip.
// ---------------------------------------------------------------------------
__global__ __launch_bounds__(256)
void attn_kernel(const u16* __restrict__ Q, const u16* __restrict__ K,
                 const u16* __restrict__ V, u16* __restrict__ O,
                 int B, int T, int NH, int HD) {
  const int tid = threadIdx.x, wave = tid >> 6, lane = tid & 63;
  const int l15 = lane & 15, quad = lane >> 4;
  const int qb0 = blockIdx.x * 64;
  const int bh = blockIdx.y, b = bh / NH, h = bh % NH;
  const float scale = 0.125f;
  __shared__ alignas(16) u16 P_lds[4][512];   // per-wave 16x32 bf16

  const size_t st = (size_t)NH * HD;          // 1024
  const size_t bhoff = (size_t)b * T * st + (size_t)h * HD;
  const u16* Qb = Q + bhoff;
  const u16* Kb = K + bhoff;
  const u16* Vb = V + bhoff;

  const u16* qp = Qb + (size_t)(qb0 + wave * 16 + l15) * st + quad * 8;
  const bf16x8 qf0 = *(const bf16x8*)qp;
  const bf16x8 qf1 = *(const bf16x8*)(qp + 32);

  float m_i[4], l_i[4];
  f32x4 oacc[4];
#pragma unroll
  for (int r = 0; r < 4; ++r) { m_i[r] = -1e30f; l_i[r] = 0.f; }
#pragma unroll
  for (int c = 0; c < 4; ++c) oacc[c] = (f32x4){0.f, 0.f, 0.f, 0.f};

  const int qrow0 = qb0 + wave * 16 + quad * 4;
  const int nkt = qb0 / 32 + 2;
  for (int kt = 0; kt < nkt; ++kt) {
    const int kb0 = kt * 32;
    const u16* kp = Kb + (size_t)(kb0 + l15) * st + quad * 8;
    const bf16x8 kf00 = *(const bf16x8*)kp;
    const bf16x8 kf01 = *(const bf16x8*)(kp + 32);
    const bf16x8 kf10 = *(const bf16x8*)(kp + 16 * st);
    const bf16x8 kf11 = *(const bf16x8*)(kp + 16 * st + 32);
    f32x4 s0 = (f32x4){0.f, 0.f, 0.f, 0.f};
    f32x4 s1 = (f32x4){0.f, 0.f, 0.f, 0.f};
    s0 = __builtin_amdgcn_mfma_f32_16x16x32_bf16(qf0, kf00, s0, 0, 0, 0);
    s0 = __builtin_amdgcn_mfma_f32_16x16x32_bf16(qf1, kf01, s0, 0, 0, 0);
    s1 = __builtin_amdgcn_mfma_f32_16x16x32_bf16(qf0, kf10, s1, 0, 0, 0);
    s1 = __builtin_amdgcn_mfma_f32_16x16x32_bf16(qf1, kf11, s1, 0, 0, 0);

    float p0[4], p1[4], tm[4];
#pragma unroll
    for (int r = 0; r < 4; ++r) {
      const int qr = qrow0 + r;
      p0[r] = (kb0 + l15 <= qr) ? s0[r] * scale : -1e30f;
      p1[r] = (kb0 + 16 + l15 <= qr) ? s1[r] * scale : -1e30f;
      tm[r] = fmaxf(p0[r], p1[r]);
    }
#pragma unroll
    for (int r = 0; r < 4; ++r) {
      tm[r] = fmaxf(tm[r], __shfl_xor(tm[r], 1, 64));
      tm[r] = fmaxf(tm[r], __shfl_xor(tm[r], 2, 64));
      tm[r] = fmaxf(tm[r], __shfl_xor(tm[r], 4, 64));
      tm[r] = fmaxf(tm[r], __shfl_xor(tm[r], 8, 64));
    }
    float alpha[4], rs[4];
#pragma unroll
    for (int r = 0; r < 4; ++r) {
      const float mn = fmaxf(m_i[r], tm[r]);
      alpha[r] = __expf(m_i[r] - mn);
      p0[r] = __expf(p0[r] - mn);
      p1[r] = __expf(p1[r] - mn);
      m_i[r] = mn;
      rs[r] = p0[r] + p1[r];
    }
#pragma unroll
    for (int r = 0; r < 4; ++r) {
      rs[r] += __shfl_xor(rs[r], 1, 64);
      rs[r] += __shfl_xor(rs[r], 2, 64);
      rs[r] += __shfl_xor(rs[r], 4, 64);
      rs[r] += __shfl_xor(rs[r], 8, 64);
      l_i[r] = l_i[r] * alpha[r] + rs[r];
    }
    // P: C-layout -> LDS -> A-layout
    u16* pl = &P_lds[wave][0];
#pragma unroll
    for (int r = 0; r < 4; ++r) {
      pl[(quad * 4 + r) * 32 + l15]      = f2b(p0[r]);
      pl[(quad * 4 + r) * 32 + 16 + l15] = f2b(p1[r]);
    }
    const bf16x8 pf = *(const bf16x8*)(pl + l15 * 32 + quad * 8);

    const u16* vp = Vb + (size_t)(kb0 + quad * 8) * st + l15;
#pragma unroll
    for (int c = 0; c < 4; ++c) {
      bf16x8 vf;
#pragma unroll
      for (int j = 0; j < 8; ++j) vf[j] = (short)vp[(size_t)j * st + c * 16];
#pragma unroll
      for (int r = 0; r < 4; ++r) oacc[c][r] *= alpha[r];
      oacc[c] = __builtin_amdgcn_mfma_f32_16x16x32_bf16(pf, vf, oacc[c], 0, 0, 0);
    }
  }

  u16* op = O + bhoff + (size_t)(qb0 + wave * 16 + quad * 4) * st + l15;
#pragma unroll
  for (int c = 0; c < 4; ++c)
#pragma unroll
    for (int r = 0; r < 4; ++r)
      op[(size_t)r * st + c * 16] = f2b(oacc[c][r] / l_i[r]);
}

// ---------------------------------------------------------------------------
// SwiGLU gate: a1 <- silu(a1) * a3, 8 bf16 elems per thread.
// ---------------------------------------------------------------------------
__global__ __launch_bounds__(256) void gate_k(u16* __restrict__ a1,
                                              const u16* __restrict__ a3) {
  const size_t i = (size_t)blockIdx.x * 256 + threadIdx.x;
  uint4 u1 = ((uint4*)a1)[i];
  const uint4 u3 = ((const uint4*)a3)[i];
  u16* p1 = (u16*)&u1;
  const u16* p3 = (const u16*)&u3;
#pragma unroll
  for (int j = 0; j < 8; ++j) {
    const float a = b2f(p1[j]);
    const float g = b2f(p3[j]);
    const float s = a / (1.f + __expf(-a));
    p1[j] = f2b(s * g);
  }
  ((uint4*)a1)[i] = u1;
}

// ---------------------------------------------------------------------------
extern "C" void kernel_launch(void* const* d_in, const int* in_sizes, int n_in,
                              void* d_out, int out_size, void* d_ws, size_t ws_size,
                              hipStream_t stream) {
  const float* x  = (const float*)d_in[0];
  // d_in[1] = mask (causal tril) — handled analytically
  const float* g1 = (const float*)d_in[2];
  const float* wq = (const float*)d_in[3];
  const float* wk = (const float*)d_in[4];
  const float* wv = (const float*)d_in[5];
  const float* wo = (const float*)d_in[6];
  const float* g2 = (const float*)d_in[7];
  const float* w1 = (const float*)d_in[8];
  const float* w2 = (const float*)d_in[9];
  const float* w3 = (const float*)d_in[10];
  float* out = (float*)d_out;

  const int B = 4, T = 2048, C = 1024, NH = 16, HD = 64;
  const int M = B * T;  // 8192

  char* ws = (char*)d_ws;
  u16* hb  = (u16*)(ws);                          // 16 MB: h bf16 (reused for h2)
  u16* wqT = (u16*)(ws + (16ull << 20));          // weight transposes (bf16)
  u16* wkT = wqT + 1024 * 1024;
  u16* wvT = wkT + 1024 * 1024;
  u16* woT = wvT + 1024 * 1024;
  u16* w1T = woT + 1024 * 1024;                   // (4096,1024)
  u16* w3T = w1T + 4096 * 1024;                   // (4096,1024)
  u16* w2T = w3T + 4096 * 1024;                   // (1024,4096)
  u16* qb  = (u16*)(ws + (48ull << 20));          // 16 MB each
  u16* kb  = qb + (size_t)M * C;
  u16* vb  = kb + (size_t)M * C;
  u16* ob  = vb + (size_t)M * C;
  u16* a1  = qb;                                  // 64 MB, overlays q/k/v/o (dead by then)
  u16* a3  = (u16*)(ws + (112ull << 20));         // 64 MB

  const dim3 tb(32, 8);
  transpose_f2b<<<dim3(32, 32),  tb, 0, stream>>>(wq, wqT, 1024, 1024);
  transpose_f2b<<<dim3(32, 32),  tb, 0, stream>>>(wk, wkT, 1024, 1024);
  transpose_f2b<<<dim3(32, 32),  tb, 0, stream>>>(wv, wvT, 1024, 1024);
  transpose_f2b<<<dim3(32, 32),  tb, 0, stream>>>(wo, woT, 1024, 1024);
  transpose_f2b<<<dim3(128, 32), tb, 0, stream>>>(w1, w1T, 1024, 4096);
  transpose_f2b<<<dim3(128, 32), tb, 0, stream>>>(w3, w3T, 1024, 4096);
  transpose_f2b<<<dim3(32, 128), tb, 0, stream>>>(w2, w2T, 4096, 1024);

  rmsnorm_k<<<M, 256, 0, stream>>>(x, g1, hb);

  gemm_bt<0><<<dim3(64, 8), 256, 0, stream>>>(hb, wqT, qb, nullptr, M, 1024, 1024);
  gemm_bt<0><<<dim3(64, 8), 256, 0, stream>>>(hb, wkT, kb, nullptr, M, 1024, 1024);
  gemm_bt<0><<<dim3(64, 8), 256, 0, stream>>>(hb, wvT, vb, nullptr, M, 1024, 1024);

  rope_k<<<16384, 256, 0, stream>>>(qb);   // B*T*NH*32 threads
  rope_k<<<16384, 256, 0, stream>>>(kb);

  attn_kernel<<<dim3(T / 64, B * NH), 256, 0, stream>>>(qb, kb, vb, ob, B, T, NH, HD);

  gemm_bt<1><<<dim3(64, 8), 256, 0, stream>>>(ob, woT, out, x, M, 1024, 1024);

  rmsnorm_k<<<M, 256, 0, stream>>>(out, g2, hb);

  gemm_bt<0><<<dim3(64, 32), 256, 0, stream>>>(hb, w1T, a1, nullptr, M, 4096, 1024);
  gemm_bt<0><<<dim3(64, 32), 256, 0, stream>>>(hb, w3T, a3, nullptr, M, 4096, 1024);

  gate_k<<<16384, 256, 0, stream>>>(a1, a3);  // M*4096/8 threads

  gemm_bt<1><<<dim3(64, 8), 256, 0, stream>>>(a1, w2T, out, out, M, 1024, 4096);
}

// Round 2
// 800.100 us; speedup vs baseline: 1.2240x; 1.2240x over previous
//
#include <hip/hip_runtime.h>
#include <cstdint>

typedef unsigned short u16;
typedef __attribute__((ext_vector_type(8))) short bf16x8;
typedef __attribute__((ext_vector_type(4))) float f32x4;

__device__ __forceinline__ u16 f2b(float f) {
  union { float f; unsigned u; } c; c.f = f;
  unsigned u = c.u;
  return (u16)((u + 0x7FFFu + ((u >> 16) & 1u)) >> 16);
}
__device__ __forceinline__ float b2f(u16 b) {
  union { unsigned u; float f; } c; c.u = ((unsigned)b) << 16;
  return c.f;
}

typedef __attribute__((address_space(1))) void gv_t;
typedef __attribute__((address_space(3))) void lv_t;
__device__ __forceinline__ void gload_lds16(const void* g, void* l) {
  __builtin_amdgcn_global_load_lds((gv_t*)g, (lv_t*)l, 16, 0, 0);
}

// ---------------------------------------------------------------------------
// Transpose + fp32->bf16 convert: out[c][r] = bf16(in[r][c]); in is R x C.
// block (32,8), grid (C/32, R/32)
// ---------------------------------------------------------------------------
__global__ void transpose_f2b(const float* __restrict__ in, u16* __restrict__ out,
                              int R, int C) {
  __shared__ float t[32][33];
  const int c0 = blockIdx.x * 32, r0 = blockIdx.y * 32;
  const int tx = threadIdx.x, ty = threadIdx.y;
#pragma unroll
  for (int i = 0; i < 4; ++i)
    t[ty + 8 * i][tx] = in[(size_t)(r0 + ty + 8 * i) * C + c0 + tx];
  __syncthreads();
#pragma unroll
  for (int i = 0; i < 4; ++i)
    out[(size_t)(c0 + ty + 8 * i) * R + r0 + tx] = f2b(t[tx][ty + 8 * i]);
}

// ---------------------------------------------------------------------------
// RMSNorm: one row (1024 fp32) per block of 256 threads; bf16 out.
// ---------------------------------------------------------------------------
__global__ __launch_bounds__(256) void rmsnorm_k(const float* __restrict__ x,
                                                 const float* __restrict__ g,
                                                 u16* __restrict__ out) {
  const int row = blockIdx.x, tid = threadIdx.x;
  const float4 v = ((const float4*)x)[(size_t)row * 256 + tid];
  float ss = v.x * v.x + v.y * v.y + v.z * v.z + v.w * v.w;
#pragma unroll
  for (int off = 1; off < 64; off <<= 1) ss += __shfl_xor(ss, off, 64);
  __shared__ float red[4];
  if ((tid & 63) == 0) red[tid >> 6] = ss;
  __syncthreads();
  const float mean = (red[0] + red[1] + red[2] + red[3]) * (1.0f / 1024.0f);
  const float rinv = 1.0f / sqrtf(mean + 1e-6f);
  const float4 gv = ((const float4*)g)[tid];
  u16* o = out + (size_t)row * 1024 + tid * 4;
  o[0] = f2b(v.x * rinv * gv.x);
  o[1] = f2b(v.y * rinv * gv.y);
  o[2] = f2b(v.z * rinv * gv.z);
  o[3] = f2b(v.w * rinv * gv.w);
}

// ---------------------------------------------------------------------------
// RoPE in-place on the fused qkv buffer (row stride 3072): rotates q (col
// offset 0) and k (col offset 1024). One thread per (b,t,h,d) pair, d<32.
// ---------------------------------------------------------------------------
__global__ __launch_bounds__(256) void rope_k(u16* __restrict__ qkv) {
  const int i = blockIdx.x * 256 + threadIdx.x;   // B*T*NH*32 total
  const int d = i & 31;
  const int h = (i >> 5) & 15;
  const int bt = i >> 9;
  const int t = bt & 2047;
  const float inv = exp2f((float)d * -0.4152410118609203f);  // 10000^(-d/32)
  const float th = (float)t * inv;
  float s, c;
  sincosf(th, &s, &c);
  size_t base = (size_t)bt * 3072 + h * 64 + d;
#pragma unroll
  for (int half = 0; half < 2; ++half) {   // q then k
    const float x1 = b2f(qkv[base]);
    const float x2 = b2f(qkv[base + 32]);
    qkv[base]      = f2b(x1 * c - x2 * s);
    qkv[base + 32] = f2b(x2 * c + x1 * s);
    base += 1024;
  }
}

// ---------------------------------------------------------------------------
// V transpose: qkv (col offset 2048, stride 3072) -> VT (b,h,d,t), u16.
// block (32,8); grid (T/32, 2*B*NH) — blockIdx.y = bh*2 + (d0/32)
// ---------------------------------------------------------------------------
__global__ void vtrans_k(const u16* __restrict__ qkv, u16* __restrict__ VT) {
  __shared__ u16 tl[32][34];
  const int t0 = blockIdx.x * 32;
  const int bh = blockIdx.y >> 1;
  const int d0 = (blockIdx.y & 1) * 32;
  const int b = bh >> 4, h = bh & 15;
  const int tx = threadIdx.x, ty = threadIdx.y;
  const u16* src = qkv + (size_t)(b * 2048 + t0) * 3072 + 2048 + h * 64 + d0;
#pragma unroll
  for (int i = 0; i < 4; ++i)
    tl[ty + 8 * i][tx] = src[(size_t)(ty + 8 * i) * 3072 + tx];
  __syncthreads();
  u16* dst = VT + ((size_t)bh * 64 + d0) * 2048 + t0;
#pragma unroll
  for (int i = 0; i < 4; ++i)
    dst[(size_t)(ty + 8 * i) * 2048 + tx] = tl[tx][ty + 8 * i];
}

// ---------------------------------------------------------------------------
// GEMM: C[M,N] = A[M,K] @ B[K,N] with BT = B^T given as (N,K) row-major bf16.
// 128x128 tile, BK=32, 256 thr, global_load_lds w16, mfma 16x16x32 bf16.
// EPI 0: bf16 store.  EPI 1: fp32 store of resid[off] + acc.
// ---------------------------------------------------------------------------
template <int EPI>
__global__ __launch_bounds__(256)
void gemm_bt(const u16* __restrict__ A, const u16* __restrict__ BT,
             void* __restrict__ Cout, const float* __restrict__ resid,
             int M, int N, int K) {
  __shared__ alignas(16) u16 As[128 * 32];
  __shared__ alignas(16) u16 Bs[128 * 32];
  const int tid = threadIdx.x;
  const int wave = tid >> 6, lane = tid & 63;
  const int wr = wave >> 1, wc = wave & 1;
  const int l15 = lane & 15, quad = lane >> 4;
  const int bm = blockIdx.x * 128, bn = blockIdx.y * 128;

  f32x4 acc[4][4];
#pragma unroll
  for (int i = 0; i < 4; ++i)
#pragma unroll
    for (int j = 0; j < 4; ++j) acc[i][j] = (f32x4){0.f, 0.f, 0.f, 0.f};

  const int srow = wave * 32 + (lane >> 2);
  const int scol = (lane & 3) * 8;
  const u16* gA0 = A + (size_t)(bm + srow) * K + scol;
  const u16* gA1 = gA0 + (size_t)16 * K;
  const u16* gB0 = BT + (size_t)(bn + srow) * K + scol;
  const u16* gB1 = gB0 + (size_t)16 * K;
  u16* lA0 = As + wave * 1024; u16* lA1 = lA0 + 512;
  u16* lB0 = Bs + wave * 1024; u16* lB1 = lB0 + 512;

  const u16* pa = As + (wr * 64 + l15) * 32 + quad * 8;
  const u16* pb = Bs + (wc * 64 + l15) * 32 + quad * 8;

  for (int kt = 0; kt < K; kt += 32) {
    gload_lds16(gA0 + kt, lA0);
    gload_lds16(gA1 + kt, lA1);
    gload_lds16(gB0 + kt, lB0);
    gload_lds16(gB1 + kt, lB1);
    __syncthreads();
    bf16x8 af[4], bfv[4];
#pragma unroll
    for (int i = 0; i < 4; ++i) af[i] = *(const bf16x8*)(pa + i * 512);
#pragma unroll
    for (int j = 0; j < 4; ++j) bfv[j] = *(const bf16x8*)(pb + j * 512);
#pragma unroll
    for (int i = 0; i < 4; ++i)
#pragma unroll
      for (int j = 0; j < 4; ++j)
        acc[i][j] = __builtin_amdgcn_mfma_f32_16x16x32_bf16(af[i], bfv[j], acc[i][j], 0, 0, 0);
    __syncthreads();
  }

#pragma unroll
  for (int i = 0; i < 4; ++i) {
    const int gr = bm + wr * 64 + i * 16 + quad * 4;
#pragma unroll
    for (int j = 0; j < 4; ++j) {
      const int gc = bn + wc * 64 + j * 16 + l15;
#pragma unroll
      for (int r = 0; r < 4; ++r) {
        const size_t off = (size_t)(gr + r) * N + gc;
        if (EPI == 0) {
          ((u16*)Cout)[off] = f2b(acc[i][j][r]);
        } else {
          ((float*)Cout)[off] = resid[off] + acc[i][j][r];
        }
      }
    }
  }
}

// ---------------------------------------------------------------------------
// Causal flash attention, Bc=64 key tiles, K/VT staged in LDS fragment-major
// via global_load_lds. Q,K from qkv (stride 3072), V from VT (b,h,d,t).
// O: (M,1024) bf16. Row sums via MFMA with all-ones B-fragment.
// Block = 4 waves = 64 q rows; wave owns 16 rows.
// ---------------------------------------------------------------------------
__global__ __launch_bounds__(256)
void attn_kernel(const u16* __restrict__ QKV, const u16* __restrict__ VT,
                 u16* __restrict__ O) {
  const int T = 2048, stQ = 3072;
  const int tid = threadIdx.x, wave = tid >> 6, lane = tid & 63;
  const int l15 = lane & 15, quad = lane >> 4;
  const int qb0 = blockIdx.x * 64;
  const int bh = blockIdx.y, b = bh >> 4, h = bh & 15;
  const float sc2 = 0.125f * 1.44269504088896f;   // scale * log2(e)

  __shared__ alignas(16) u16 Kf[8 * 512];   // fragment-major [g=jj*2+hh][lane*8]
  __shared__ alignas(16) u16 Vf[8 * 512];   // fragment-major [g=c*2+h2][lane*8]
  __shared__ alignas(16) u16 Pl[4][16 * 72];

  const u16* Qb  = QKV + (size_t)b * T * stQ + h * 64;
  const u16* Kb  = Qb + 1024;
  const u16* VTb = VT + (size_t)bh * 64 * T;

  // Q fragments (A-operand: lane holds Q[m=l15][k=quad*8+j])
  const u16* qp = Qb + (size_t)(qb0 + wave * 16 + l15) * stQ + quad * 8;
  const bf16x8 qf0 = *(const bf16x8*)qp;
  const bf16x8 qf1 = *(const bf16x8*)(qp + 32);

  bf16x8 ones;
#pragma unroll
  for (int j = 0; j < 8; ++j) ones[j] = (short)0x3F80;   // bf16 1.0

  // staging source bases (lane-permuted so LDS lands fragment-major):
  // wave w stages s-tile jj=w, issue i = half hh
  const u16* kS = Kb + (size_t)(wave * 16 + l15) * stQ + quad * 8;
  const u16* vS = VTb + (size_t)(wave * 16 + l15) * T + quad * 8;
  u16* kD0 = Kf + (wave * 2 + 0) * 512;  u16* kD1 = Kf + (wave * 2 + 1) * 512;
  u16* vD0 = Vf + (wave * 2 + 0) * 512;  u16* vD1 = Vf + (wave * 2 + 1) * 512;

  float m2[4];
  f32x4 oacc[4], osum;
#pragma unroll
  for (int r = 0; r < 4; ++r) m2[r] = -1e30f;
#pragma unroll
  for (int c = 0; c < 4; ++c) oacc[c] = (f32x4){0.f, 0.f, 0.f, 0.f};
  osum = (f32x4){0.f, 0.f, 0.f, 0.f};

  const int qrow0 = qb0 + wave * 16 + quad * 4;
  const int nkt = qb0 / 64 + 1;
  for (int kt = 0; kt < nkt; ++kt) {
    const int kb0 = kt * 64;
    gload_lds16(kS + (size_t)kb0 * stQ,      kD0);
    gload_lds16(kS + (size_t)kb0 * stQ + 32, kD1);
    gload_lds16(vS + kb0,                    vD0);
    gload_lds16(vS + kb0 + 32,               vD1);
    __syncthreads();

    // QK^T: 4 s-tiles of 16 keys
    f32x4 s[4];
#pragma unroll
    for (int jj = 0; jj < 4; ++jj) {
      s[jj] = (f32x4){0.f, 0.f, 0.f, 0.f};
      const bf16x8 k0 = *(const bf16x8*)(Kf + (jj * 2 + 0) * 512 + lane * 8);
      const bf16x8 k1 = *(const bf16x8*)(Kf + (jj * 2 + 1) * 512 + lane * 8);
      s[jj] = __builtin_amdgcn_mfma_f32_16x16x32_bf16(qf0, k0, s[jj], 0, 0, 0);
      s[jj] = __builtin_amdgcn_mfma_f32_16x16x32_bf16(qf1, k1, s[jj], 0, 0, 0);
    }

    float a_[4][4];
#pragma unroll
    for (int jj = 0; jj < 4; ++jj)
#pragma unroll
      for (int r = 0; r < 4; ++r) a_[jj][r] = s[jj][r] * sc2;
    if (kb0 + 63 > qb0 + wave * 16) {   // diagonal tile: apply causal mask
#pragma unroll
      for (int jj = 0; jj < 4; ++jj)
#pragma unroll
        for (int r = 0; r < 4; ++r)
          if (kb0 + jj * 16 + l15 > qrow0 + r) a_[jj][r] = -1e30f;
    }
    float tm[4];
#pragma unroll
    for (int r = 0; r < 4; ++r)
      tm[r] = fmaxf(fmaxf(a_[0][r], a_[1][r]), fmaxf(a_[2][r], a_[3][r]));
#pragma unroll
    for (int r = 0; r < 4; ++r) {
      tm[r] = fmaxf(tm[r], __shfl_xor(tm[r], 1, 64));
      tm[r] = fmaxf(tm[r], __shfl_xor(tm[r], 2, 64));
      tm[r] = fmaxf(tm[r], __shfl_xor(tm[r], 4, 64));
      tm[r] = fmaxf(tm[r], __shfl_xor(tm[r], 8, 64));
    }
    float al[4];
#pragma unroll
    for (int r = 0; r < 4; ++r) {
      const float mn = fmaxf(m2[r], tm[r]);
      al[r] = exp2f(m2[r] - mn);
      m2[r] = mn;
    }
    u16* pw = &Pl[wave][0];
#pragma unroll
    for (int jj = 0; jj < 4; ++jj)
#pragma unroll
      for (int r = 0; r < 4; ++r)
        pw[(quad * 4 + r) * 72 + jj * 16 + l15] = f2b(exp2f(a_[jj][r] - m2[r]));
#pragma unroll
    for (int c = 0; c < 4; ++c)
#pragma unroll
      for (int r = 0; r < 4; ++r) oacc[c][r] *= al[r];
#pragma unroll
    for (int r = 0; r < 4; ++r) osum[r] *= al[r];

    const bf16x8 pf0 = *(const bf16x8*)(pw + l15 * 72 + quad * 8);
    const bf16x8 pf1 = *(const bf16x8*)(pw + l15 * 72 + 32 + quad * 8);
#pragma unroll
    for (int c = 0; c < 4; ++c) {
      const bf16x8 v0 = *(const bf16x8*)(Vf + (c * 2 + 0) * 512 + lane * 8);
      const bf16x8 v1 = *(const bf16x8*)(Vf + (c * 2 + 1) * 512 + lane * 8);
      oacc[c] = __builtin_amdgcn_mfma_f32_16x16x32_bf16(pf0, v0, oacc[c], 0, 0, 0);
      oacc[c] = __builtin_amdgcn_mfma_f32_16x16x32_bf16(pf1, v1, oacc[c], 0, 0, 0);
    }
    osum = __builtin_amdgcn_mfma_f32_16x16x32_bf16(pf0, ones, osum, 0, 0, 0);
    osum = __builtin_amdgcn_mfma_f32_16x16x32_bf16(pf1, ones, osum, 0, 0, 0);
    __syncthreads();
  }

  float inv[4];
#pragma unroll
  for (int r = 0; r < 4; ++r) inv[r] = 1.f / osum[r];
  u16* op = O + ((size_t)(b * T) + qb0 + wave * 16 + quad * 4) * 1024 + h * 64 + l15;
#pragma unroll
  for (int c = 0; c < 4; ++c)
#pragma unroll
    for (int r = 0; r < 4; ++r)
      op[(size_t)r * 1024 + c * 16] = f2b(oacc[c][r] * inv[r]);
}

// ---------------------------------------------------------------------------
// SwiGLU gate, in-place: a1 <- silu(a1) * a3, 8 bf16 elems per thread.
// ---------------------------------------------------------------------------
__global__ __launch_bounds__(256) void gate_k(u16* __restrict__ a1,
                                              const u16* __restrict__ a3) {
  const size_t i = (size_t)blockIdx.x * 256 + threadIdx.x;
  uint4 u1 = ((uint4*)a1)[i];
  const uint4 u3 = ((const uint4*)a3)[i];
  u16* p1 = (u16*)&u1;
  const u16* p3 = (const u16*)&u3;
#pragma unroll
  for (int j = 0; j < 8; ++j) {
    const float a = b2f(p1[j]);
    const float g = b2f(p3[j]);
    const float s = a / (1.f + __expf(-a));
    p1[j] = f2b(s * g);
  }
  ((uint4*)a1)[i] = u1;
}

// ---------------------------------------------------------------------------
extern "C" void kernel_launch(void* const* d_in, const int* in_sizes, int n_in,
                              void* d_out, int out_size, void* d_ws, size_t ws_size,
                              hipStream_t stream) {
  const float* x  = (const float*)d_in[0];
  const float* g1 = (const float*)d_in[2];
  const float* wq = (const float*)d_in[3];
  const float* wk = (const float*)d_in[4];
  const float* wv = (const float*)d_in[5];
  const float* wo = (const float*)d_in[6];
  const float* g2 = (const float*)d_in[7];
  const float* w1 = (const float*)d_in[8];
  const float* w2 = (const float*)d_in[9];
  const float* w3 = (const float*)d_in[10];
  float* out = (float*)d_out;

  const int T = 2048, NH = 16;
  const int B = 4;
  const int M = B * T;  // 8192
  const size_t MB = 1ull << 20;

  char* ws = (char*)d_ws;
  u16* hb    = (u16*)(ws);              // 16 MB
  u16* wqkvT = (u16*)(ws + 16 * MB);    // 6 MB (3072 x 1024)
  u16* woT   = (u16*)(ws + 22 * MB);    // 2 MB
  u16* w1T   = (u16*)(ws + 24 * MB);    // 8 MB (4096 x 1024)
  u16* w3T   = (u16*)(ws + 32 * MB);    // 8 MB
  u16* w2T   = (u16*)(ws + 40 * MB);    // 8 MB (1024 x 4096)
  u16* qkv   = (u16*)(ws + 48 * MB);    // 48 MB (M x 3072)
  u16* VT    = (u16*)(ws + 96 * MB);    // 16 MB (b,h,d,t)
  u16* Ob    = (u16*)(ws + 112 * MB);   // 16 MB
  u16* a1    = (u16*)(ws + 48 * MB);    // 64 MB (overlays qkv+VT, dead)
  u16* a3    = (u16*)(ws + 112 * MB);   // 64 MB (overlays Ob, dead)

  const dim3 tb(32, 8);
  transpose_f2b<<<dim3(32, 32),  tb, 0, stream>>>(wq, wqkvT,              1024, 1024);
  transpose_f2b<<<dim3(32, 32),  tb, 0, stream>>>(wk, wqkvT + 1024*1024,  1024, 1024);
  transpose_f2b<<<dim3(32, 32),  tb, 0, stream>>>(wv, wqkvT + 2048*1024,  1024, 1024);
  transpose_f2b<<<dim3(32, 32),  tb, 0, stream>>>(wo, woT, 1024, 1024);
  transpose_f2b<<<dim3(128, 32), tb, 0, stream>>>(w1, w1T, 1024, 4096);
  transpose_f2b<<<dim3(128, 32), tb, 0, stream>>>(w3, w3T, 1024, 4096);
  transpose_f2b<<<dim3(32, 128), tb, 0, stream>>>(w2, w2T, 4096, 1024);

  rmsnorm_k<<<M, 256, 0, stream>>>(x, g1, hb);

  gemm_bt<0><<<dim3(64, 24), 256, 0, stream>>>(hb, wqkvT, qkv, nullptr, M, 3072, 1024);

  rope_k<<<16384, 256, 0, stream>>>(qkv);               // q and k
  vtrans_k<<<dim3(64, 128), tb, 0, stream>>>(qkv, VT);  // v -> (b,h,d,t)

  attn_kernel<<<dim3(T / 64, B * NH), 256, 0, stream>>>(qkv, VT, Ob);

  gemm_bt<1><<<dim3(64, 8), 256, 0, stream>>>(Ob, woT, out, x, M, 1024, 1024);

  rmsnorm_k<<<M, 256, 0, stream>>>(out, g2, hb);

  gemm_bt<0><<<dim3(64, 32), 256, 0, stream>>>(hb, w1T, a1, nullptr, M, 4096, 1024);
  gemm_bt<0><<<dim3(64, 32), 256, 0, stream>>>(hb, w3T, a3, nullptr, M, 4096, 1024);

  gate_k<<<16384, 256, 0, stream>>>(a1, a3);

  gemm_bt<1><<<dim3(64, 8), 256, 0, stream>>>(a1, w2T, out, out, M, 1024, 4096);
}

// Round 4
// 798.454 us; speedup vs baseline: 1.2265x; 1.0021x over previous
//
#include <hip/hip_runtime.h>
#include <cstdint>

typedef unsigned short u16;
typedef __attribute__((ext_vector_type(8))) short bf16x8;
typedef __attribute__((ext_vector_type(4))) float f32x4;

__device__ __forceinline__ u16 f2b(float f) {
  union { float f; unsigned u; } c; c.f = f;
  unsigned u = c.u;
  return (u16)((u + 0x7FFFu + ((u >> 16) & 1u)) >> 16);
}
__device__ __forceinline__ float b2f(u16 b) {
  union { unsigned u; float f; } c; c.u = ((unsigned)b) << 16;
  return c.f;
}

typedef __attribute__((address_space(1))) void gv_t;
typedef __attribute__((address_space(3))) void lv_t;
__device__ __forceinline__ void gload_lds16(const void* g, void* l) {
  __builtin_amdgcn_global_load_lds((gv_t*)g, (lv_t*)l, 16, 0, 0);
}

// ---------------------------------------------------------------------------
// Transpose + fp32->bf16 convert: out[c][r] = bf16(in[r][c]); in is R x C.
// block (32,8), grid (C/32, R/32)
// ---------------------------------------------------------------------------
__global__ void transpose_f2b(const float* __restrict__ in, u16* __restrict__ out,
                              int R, int C) {
  __shared__ float t[32][33];
  const int c0 = blockIdx.x * 32, r0 = blockIdx.y * 32;
  const int tx = threadIdx.x, ty = threadIdx.y;
#pragma unroll
  for (int i = 0; i < 4; ++i)
    t[ty + 8 * i][tx] = in[(size_t)(r0 + ty + 8 * i) * C + c0 + tx];
  __syncthreads();
#pragma unroll
  for (int i = 0; i < 4; ++i)
    out[(size_t)(c0 + ty + 8 * i) * R + r0 + tx] = f2b(t[tx][ty + 8 * i]);
}

// ---------------------------------------------------------------------------
// RMSNorm: one row (1024 fp32) per block of 256 threads; bf16 out.
// ---------------------------------------------------------------------------
__global__ __launch_bounds__(256) void rmsnorm_k(const float* __restrict__ x,
                                                 const float* __restrict__ g,
                                                 u16* __restrict__ out) {
  const int row = blockIdx.x, tid = threadIdx.x;
  const float4 v = ((const float4*)x)[(size_t)row * 256 + tid];
  float ss = v.x * v.x + v.y * v.y + v.z * v.z + v.w * v.w;
#pragma unroll
  for (int off = 1; off < 64; off <<= 1) ss += __shfl_xor(ss, off, 64);
  __shared__ float red[4];
  if ((tid & 63) == 0) red[tid >> 6] = ss;
  __syncthreads();
  const float mean = (red[0] + red[1] + red[2] + red[3]) * (1.0f / 1024.0f);
  const float rinv = 1.0f / sqrtf(mean + 1e-6f);
  const float4 gv = ((const float4*)g)[tid];
  u16* o = out + (size_t)row * 1024 + tid * 4;
  o[0] = f2b(v.x * rinv * gv.x);
  o[1] = f2b(v.y * rinv * gv.y);
  o[2] = f2b(v.z * rinv * gv.z);
  o[3] = f2b(v.w * rinv * gv.w);
}

// ---------------------------------------------------------------------------
// RoPE in-place on fused qkv (row stride 3072): rotates q and k halves.
// ---------------------------------------------------------------------------
__global__ __launch_bounds__(256) void rope_k(u16* __restrict__ qkv) {
  const int i = blockIdx.x * 256 + threadIdx.x;   // B*T*NH*32 total
  const int d = i & 31;
  const int h = (i >> 5) & 15;
  const int bt = i >> 9;
  const int t = bt & 2047;
  const float inv = exp2f((float)d * -0.4152410118609203f);  // 10000^(-d/32)
  const float th = (float)t * inv;
  float s, c;
  sincosf(th, &s, &c);
  size_t base = (size_t)bt * 3072 + h * 64 + d;
#pragma unroll
  for (int half = 0; half < 2; ++half) {   // q then k
    const float x1 = b2f(qkv[base]);
    const float x2 = b2f(qkv[base + 32]);
    qkv[base]      = f2b(x1 * c - x2 * s);
    qkv[base + 32] = f2b(x2 * c + x1 * s);
    base += 1024;
  }
}

// ---------------------------------------------------------------------------
// V transpose: qkv (col offset 2048, stride 3072) -> VT (b,h,d,t), u16.
// block (32,8); grid (T/32, 2*B*NH)
// ---------------------------------------------------------------------------
__global__ void vtrans_k(const u16* __restrict__ qkv, u16* __restrict__ VT) {
  __shared__ u16 tl[32][34];
  const int t0 = blockIdx.x * 32;
  const int bh = blockIdx.y >> 1;
  const int d0 = (blockIdx.y & 1) * 32;
  const int b = bh >> 4, h = bh & 15;
  const int tx = threadIdx.x, ty = threadIdx.y;
  const u16* src = qkv + (size_t)(b * 2048 + t0) * 3072 + 2048 + h * 64 + d0;
#pragma unroll
  for (int i = 0; i < 4; ++i)
    tl[ty + 8 * i][tx] = src[(size_t)(ty + 8 * i) * 3072 + tx];
  __syncthreads();
  u16* dst = VT + ((size_t)bh * 64 + d0) * 2048 + t0;
#pragma unroll
  for (int i = 0; i < 4; ++i)
    dst[(size_t)(ty + 8 * i) * 2048 + tx] = tl[tx][ty + 8 * i];
}

// ---------------------------------------------------------------------------
// GEMM: C[M,N] = A[M,K] @ B[K,N], BT = B^T (N,K) row-major bf16; A row stride
// lda. 128x128 tile, BK=32, 256 thr, global_load_lds w16, mfma 16x16x32 bf16.
// EPI 0: bf16 store.  EPI 1: fp32 store of resid[off] + acc.
// ---------------------------------------------------------------------------
template <int EPI>
__global__ __launch_bounds__(256)
void gemm_bt(const u16* __restrict__ A, const u16* __restrict__ BT,
             void* __restrict__ Cout, const float* __restrict__ resid,
             int M, int N, int K, int lda) {
  __shared__ alignas(16) u16 As[128 * 32];
  __shared__ alignas(16) u16 Bs[128 * 32];
  const int tid = threadIdx.x;
  const int wave = tid >> 6, lane = tid & 63;
  const int wr = wave >> 1, wc = wave & 1;
  const int l15 = lane & 15, quad = lane >> 4;
  const int bm = blockIdx.x * 128, bn = blockIdx.y * 128;

  f32x4 acc[4][4];
#pragma unroll
  for (int i = 0; i < 4; ++i)
#pragma unroll
    for (int j = 0; j < 4; ++j) acc[i][j] = (f32x4){0.f, 0.f, 0.f, 0.f};

  const int srow = wave * 32 + (lane >> 2);
  const int scol = (lane & 3) * 8;
  const u16* gA0 = A + (size_t)(bm + srow) * lda + scol;
  const u16* gA1 = gA0 + (size_t)16 * lda;
  const u16* gB0 = BT + (size_t)(bn + srow) * K + scol;
  const u16* gB1 = gB0 + (size_t)16 * K;
  u16* lA0 = As + wave * 1024; u16* lA1 = lA0 + 512;
  u16* lB0 = Bs + wave * 1024; u16* lB1 = lB0 + 512;

  const u16* pa = As + (wr * 64 + l15) * 32 + quad * 8;
  const u16* pb = Bs + (wc * 64 + l15) * 32 + quad * 8;

  for (int kt = 0; kt < K; kt += 32) {
    gload_lds16(gA0 + kt, lA0);
    gload_lds16(gA1 + kt, lA1);
    gload_lds16(gB0 + kt, lB0);
    gload_lds16(gB1 + kt, lB1);
    __syncthreads();
    bf16x8 af[4], bfv[4];
#pragma unroll
    for (int i = 0; i < 4; ++i) af[i] = *(const bf16x8*)(pa + i * 512);
#pragma unroll
    for (int j = 0; j < 4; ++j) bfv[j] = *(const bf16x8*)(pb + j * 512);
#pragma unroll
    for (int i = 0; i < 4; ++i)
#pragma unroll
      for (int j = 0; j < 4; ++j)
        acc[i][j] = __builtin_amdgcn_mfma_f32_16x16x32_bf16(af[i], bfv[j], acc[i][j], 0, 0, 0);
    __syncthreads();
  }

#pragma unroll
  for (int i = 0; i < 4; ++i) {
    const int gr = bm + wr * 64 + i * 16 + quad * 4;
#pragma unroll
    for (int j = 0; j < 4; ++j) {
      const int gc = bn + wc * 64 + j * 16 + l15;
#pragma unroll
      for (int r = 0; r < 4; ++r) {
        const size_t off = (size_t)(gr + r) * N + gc;
        if (EPI == 0) {
          ((u16*)Cout)[off] = f2b(acc[i][j][r]);
        } else {
          ((float*)Cout)[off] = resid[off] + acc[i][j][r];
        }
      }
    }
  }
}

// ---------------------------------------------------------------------------
// Causal flash attention (round-2 proven kernel + LPT block-ID reversal only).
// Bc=64 key tiles, K/VT staged in LDS fragment-major via global_load_lds.
// Q,K from qkv (stride 3072), V from VT (b,h,d,t). O: (M,1024) bf16.
// Row sums via MFMA with all-ones B-fragment. Block = 4 waves = 64 q rows.
// ---------------------------------------------------------------------------
__global__ __launch_bounds__(256)
void attn_kernel(const u16* __restrict__ QKV, const u16* __restrict__ VT,
                 u16* __restrict__ O) {
  const int T = 2048, stQ = 3072;
  const int tid = threadIdx.x, wave = tid >> 6, lane = tid & 63;
  const int l15 = lane & 15, quad = lane >> 4;
  const int qb0 = ((int)gridDim.x - 1 - (int)blockIdx.x) * 64;  // LPT: longest first
  const int bh = blockIdx.y, b = bh >> 4, h = bh & 15;
  const float sc2 = 0.125f * 1.44269504088896f;   // scale * log2(e)

  __shared__ alignas(16) u16 Kf[8 * 512];   // fragment-major [g=jj*2+hh][lane*8]
  __shared__ alignas(16) u16 Vf[8 * 512];   // fragment-major [g=c*2+h2][lane*8]
  __shared__ alignas(16) u16 Pl[4][16 * 72];

  const u16* Qb  = QKV + (size_t)b * T * stQ + h * 64;
  const u16* Kb  = Qb + 1024;
  const u16* VTb = VT + (size_t)bh * 64 * T;

  // Q fragments (A-operand: lane holds Q[m=l15][k=quad*8+j])
  const u16* qp = Qb + (size_t)(qb0 + wave * 16 + l15) * stQ + quad * 8;
  const bf16x8 qf0 = *(const bf16x8*)qp;
  const bf16x8 qf1 = *(const bf16x8*)(qp + 32);

  bf16x8 ones;
#pragma unroll
  for (int j = 0; j < 8; ++j) ones[j] = (short)0x3F80;   // bf16 1.0

  // staging source bases (lane-permuted so LDS lands fragment-major):
  const u16* kS = Kb + (size_t)(wave * 16 + l15) * stQ + quad * 8;
  const u16* vS = VTb + (size_t)(wave * 16 + l15) * T + quad * 8;
  u16* kD0 = Kf + (wave * 2 + 0) * 512;  u16* kD1 = Kf + (wave * 2 + 1) * 512;
  u16* vD0 = Vf + (wave * 2 + 0) * 512;  u16* vD1 = Vf + (wave * 2 + 1) * 512;

  float m2[4];
  f32x4 oacc[4], osum;
#pragma unroll
  for (int r = 0; r < 4; ++r) m2[r] = -1e30f;
#pragma unroll
  for (int c = 0; c < 4; ++c) oacc[c] = (f32x4){0.f, 0.f, 0.f, 0.f};
  osum = (f32x4){0.f, 0.f, 0.f, 0.f};

  const int qrow0 = qb0 + wave * 16 + quad * 4;
  const int nkt = qb0 / 64 + 1;
  for (int kt = 0; kt < nkt; ++kt) {
    const int kb0 = kt * 64;
    gload_lds16(kS + (size_t)kb0 * stQ,      kD0);
    gload_lds16(kS + (size_t)kb0 * stQ + 32, kD1);
    gload_lds16(vS + kb0,                    vD0);
    gload_lds16(vS + kb0 + 32,               vD1);
    __syncthreads();

    // QK^T: 4 s-tiles of 16 keys
    f32x4 s[4];
#pragma unroll
    for (int jj = 0; jj < 4; ++jj) {
      s[jj] = (f32x4){0.f, 0.f, 0.f, 0.f};
      const bf16x8 k0 = *(const bf16x8*)(Kf + (jj * 2 + 0) * 512 + lane * 8);
      const bf16x8 k1 = *(const bf16x8*)(Kf + (jj * 2 + 1) * 512 + lane * 8);
      s[jj] = __builtin_amdgcn_mfma_f32_16x16x32_bf16(qf0, k0, s[jj], 0, 0, 0);
      s[jj] = __builtin_amdgcn_mfma_f32_16x16x32_bf16(qf1, k1, s[jj], 0, 0, 0);
    }

    float a_[4][4];
#pragma unroll
    for (int jj = 0; jj < 4; ++jj)
#pragma unroll
      for (int r = 0; r < 4; ++r) a_[jj][r] = s[jj][r] * sc2;
    if (kb0 + 63 > qb0 + wave * 16) {   // diagonal tile: apply causal mask
#pragma unroll
      for (int jj = 0; jj < 4; ++jj)
#pragma unroll
        for (int r = 0; r < 4; ++r)
          if (kb0 + jj * 16 + l15 > qrow0 + r) a_[jj][r] = -1e30f;
    }
    float tm[4];
#pragma unroll
    for (int r = 0; r < 4; ++r)
      tm[r] = fmaxf(fmaxf(a_[0][r], a_[1][r]), fmaxf(a_[2][r], a_[3][r]));
#pragma unroll
    for (int r = 0; r < 4; ++r) {
      tm[r] = fmaxf(tm[r], __shfl_xor(tm[r], 1, 64));
      tm[r] = fmaxf(tm[r], __shfl_xor(tm[r], 2, 64));
      tm[r] = fmaxf(tm[r], __shfl_xor(tm[r], 4, 64));
      tm[r] = fmaxf(tm[r], __shfl_xor(tm[r], 8, 64));
    }
    float al[4];
#pragma unroll
    for (int r = 0; r < 4; ++r) {
      const float mn = fmaxf(m2[r], tm[r]);
      al[r] = exp2f(m2[r] - mn);
      m2[r] = mn;
    }
    u16* pw = &Pl[wave][0];
#pragma unroll
    for (int jj = 0; jj < 4; ++jj)
#pragma unroll
      for (int r = 0; r < 4; ++r)
        pw[(quad * 4 + r) * 72 + jj * 16 + l15] = f2b(exp2f(a_[jj][r] - m2[r]));
#pragma unroll
    for (int c = 0; c < 4; ++c)
#pragma unroll
      for (int r = 0; r < 4; ++r) oacc[c][r] *= al[r];
#pragma unroll
    for (int r = 0; r < 4; ++r) osum[r] *= al[r];

    const bf16x8 pf0 = *(const bf16x8*)(pw + l15 * 72 + quad * 8);
    const bf16x8 pf1 = *(const bf16x8*)(pw + l15 * 72 + 32 + quad * 8);
#pragma unroll
    for (int c = 0; c < 4; ++c) {
      const bf16x8 v0 = *(const bf16x8*)(Vf + (c * 2 + 0) * 512 + lane * 8);
      const bf16x8 v1 = *(const bf16x8*)(Vf + (c * 2 + 1) * 512 + lane * 8);
      oacc[c] = __builtin_amdgcn_mfma_f32_16x16x32_bf16(pf0, v0, oacc[c], 0, 0, 0);
      oacc[c] = __builtin_amdgcn_mfma_f32_16x16x32_bf16(pf1, v1, oacc[c], 0, 0, 0);
    }
    osum = __builtin_amdgcn_mfma_f32_16x16x32_bf16(pf0, ones, osum, 0, 0, 0);
    osum = __builtin_amdgcn_mfma_f32_16x16x32_bf16(pf1, ones, osum, 0, 0, 0);
    __syncthreads();
  }

  float inv[4];
#pragma unroll
  for (int r = 0; r < 4; ++r) inv[r] = 1.f / osum[r];
  u16* op = O + ((size_t)(b * T) + qb0 + wave * 16 + quad * 4) * 1024 + h * 64 + l15;
#pragma unroll
  for (int c = 0; c < 4; ++c)
#pragma unroll
    for (int r = 0; r < 4; ++r)
      op[(size_t)r * 1024 + c * 16] = f2b(oacc[c][r] * inv[r]);
}

// ---------------------------------------------------------------------------
// SwiGLU gate, in-place on fused a13 (M x 8192): first half <- silu(a1)*a3.
// ---------------------------------------------------------------------------
__global__ __launch_bounds__(256) void gate_k(u16* __restrict__ a13) {
  const size_t i = (size_t)blockIdx.x * 256 + threadIdx.x;
  const size_t row = i >> 9, c8 = (i & 511) * 8;
  u16* p1v = a13 + row * 8192 + c8;
  const u16* p3v = p1v + 4096;
  uint4 u1 = *(uint4*)p1v;
  const uint4 u3 = *(const uint4*)p3v;
  u16* p1 = (u16*)&u1;
  const u16* p3 = (const u16*)&u3;
#pragma unroll
  for (int j = 0; j < 8; ++j) {
    const float a = b2f(p1[j]);
    const float g = b2f(p3[j]);
    const float s = a / (1.f + __expf(-a));
    p1[j] = f2b(s * g);
  }
  *(uint4*)p1v = u1;
}

// ---------------------------------------------------------------------------
extern "C" void kernel_launch(void* const* d_in, const int* in_sizes, int n_in,
                              void* d_out, int out_size, void* d_ws, size_t ws_size,
                              hipStream_t stream) {
  const float* x  = (const float*)d_in[0];
  const float* g1 = (const float*)d_in[2];
  const float* wq = (const float*)d_in[3];
  const float* wk = (const float*)d_in[4];
  const float* wv = (const float*)d_in[5];
  const float* wo = (const float*)d_in[6];
  const float* g2 = (const float*)d_in[7];
  const float* w1 = (const float*)d_in[8];
  const float* w2 = (const float*)d_in[9];
  const float* w3 = (const float*)d_in[10];
  float* out = (float*)d_out;

  const int T = 2048, NH = 16, B = 4;
  const int M = B * T;  // 8192
  const size_t MB = 1ull << 20;

  char* ws = (char*)d_ws;
  u16* hb    = (u16*)(ws);              // 16 MB
  u16* wqkvT = (u16*)(ws + 16 * MB);    // 6 MB (3072 x 1024)
  u16* woT   = (u16*)(ws + 22 * MB);    // 2 MB
  u16* w13T  = (u16*)(ws + 24 * MB);    // 16 MB (8192 x 1024: w1T then w3T)
  u16* w2T   = (u16*)(ws + 40 * MB);    // 8 MB (1024 x 4096)
  u16* qkv   = (u16*)(ws + 48 * MB);    // 48 MB (M x 3072)
  u16* VT    = (u16*)(ws + 96 * MB);    // 16 MB (b,h,d,t)
  u16* Ob    = (u16*)(ws + 112 * MB);   // 16 MB
  u16* a13   = (u16*)(ws + 48 * MB);    // 128 MB (M x 8192), overlays qkv/VT/Ob

  const dim3 tb(32, 8);
  transpose_f2b<<<dim3(32, 32),  tb, 0, stream>>>(wq, wqkvT,              1024, 1024);
  transpose_f2b<<<dim3(32, 32),  tb, 0, stream>>>(wk, wqkvT + 1024*1024,  1024, 1024);
  transpose_f2b<<<dim3(32, 32),  tb, 0, stream>>>(wv, wqkvT + 2048*1024,  1024, 1024);
  transpose_f2b<<<dim3(32, 32),  tb, 0, stream>>>(wo, woT, 1024, 1024);
  transpose_f2b<<<dim3(128, 32), tb, 0, stream>>>(w1, w13T,               1024, 4096);
  transpose_f2b<<<dim3(128, 32), tb, 0, stream>>>(w3, w13T + 4096*1024,   1024, 4096);
  transpose_f2b<<<dim3(32, 128), tb, 0, stream>>>(w2, w2T, 4096, 1024);

  rmsnorm_k<<<M, 256, 0, stream>>>(x, g1, hb);

  gemm_bt<0><<<dim3(64, 24), 256, 0, stream>>>(hb, wqkvT, qkv, nullptr, M, 3072, 1024, 1024);

  rope_k<<<16384, 256, 0, stream>>>(qkv);
  vtrans_k<<<dim3(64, 128), tb, 0, stream>>>(qkv, VT);

  attn_kernel<<<dim3(T / 64, B * NH), 256, 0, stream>>>(qkv, VT, Ob);

  gemm_bt<1><<<dim3(64, 8), 256, 0, stream>>>(Ob, woT, out, x, M, 1024, 1024, 1024);

  rmsnorm_k<<<M, 256, 0, stream>>>(out, g2, hb);

  gemm_bt<0><<<dim3(64, 64), 256, 0, stream>>>(hb, w13T, a13, nullptr, M, 8192, 1024, 1024);

  gate_k<<<16384, 256, 0, stream>>>(a13);

  gemm_bt<1><<<dim3(64, 8), 256, 0, stream>>>(a13, w2T, out, out, M, 1024, 4096, 8192);
}

// Round 5
// 760.303 us; speedup vs baseline: 1.2881x; 1.0502x over previous
//
#include <hip/hip_runtime.h>
#include <cstdint>

typedef unsigned short u16;
typedef __attribute__((ext_vector_type(8))) short bf16x8;
typedef __attribute__((ext_vector_type(4))) float f32x4;

__device__ __forceinline__ u16 f2b(float f) {
  union { float f; unsigned u; } c; c.f = f;
  unsigned u = c.u;
  return (u16)((u + 0x7FFFu + ((u >> 16) & 1u)) >> 16);
}
__device__ __forceinline__ float b2f(u16 b) {
  union { unsigned u; float f; } c; c.u = ((unsigned)b) << 16;
  return c.f;
}

typedef __attribute__((address_space(1))) void gv_t;
typedef __attribute__((address_space(3))) void lv_t;
__device__ __forceinline__ void gload_lds16(const void* g, void* l) {
  __builtin_amdgcn_global_load_lds((gv_t*)g, (lv_t*)l, 16, 0, 0);
}

// ---------------------------------------------------------------------------
// Transpose + fp32->bf16 convert: out[c][r] = bf16(in[r][c]); in is R x C.
// block (32,8), grid (C/32, R/32)
// ---------------------------------------------------------------------------
__global__ void transpose_f2b(const float* __restrict__ in, u16* __restrict__ out,
                              int R, int C) {
  __shared__ float t[32][33];
  const int c0 = blockIdx.x * 32, r0 = blockIdx.y * 32;
  const int tx = threadIdx.x, ty = threadIdx.y;
#pragma unroll
  for (int i = 0; i < 4; ++i)
    t[ty + 8 * i][tx] = in[(size_t)(r0 + ty + 8 * i) * C + c0 + tx];
  __syncthreads();
#pragma unroll
  for (int i = 0; i < 4; ++i)
    out[(size_t)(c0 + ty + 8 * i) * R + r0 + tx] = f2b(t[tx][ty + 8 * i]);
}

// ---------------------------------------------------------------------------
// RMSNorm: one row (1024 fp32) per block of 256 threads; bf16 out.
// ---------------------------------------------------------------------------
__global__ __launch_bounds__(256) void rmsnorm_k(const float* __restrict__ x,
                                                 const float* __restrict__ g,
                                                 u16* __restrict__ out) {
  const int row = blockIdx.x, tid = threadIdx.x;
  const float4 v = ((const float4*)x)[(size_t)row * 256 + tid];
  float ss = v.x * v.x + v.y * v.y + v.z * v.z + v.w * v.w;
#pragma unroll
  for (int off = 1; off < 64; off <<= 1) ss += __shfl_xor(ss, off, 64);
  __shared__ float red[4];
  if ((tid & 63) == 0) red[tid >> 6] = ss;
  __syncthreads();
  const float mean = (red[0] + red[1] + red[2] + red[3]) * (1.0f / 1024.0f);
  const float rinv = 1.0f / sqrtf(mean + 1e-6f);
  const float4 gv = ((const float4*)g)[tid];
  u16* o = out + (size_t)row * 1024 + tid * 4;
  o[0] = f2b(v.x * rinv * gv.x);
  o[1] = f2b(v.y * rinv * gv.y);
  o[2] = f2b(v.z * rinv * gv.z);
  o[3] = f2b(v.w * rinv * gv.w);
}

// ---------------------------------------------------------------------------
// RoPE in-place on fused qkv (row stride 3072): rotates q and k halves.
// ---------------------------------------------------------------------------
__global__ __launch_bounds__(256) void rope_k(u16* __restrict__ qkv) {
  const int i = blockIdx.x * 256 + threadIdx.x;   // B*T*NH*32 total
  const int d = i & 31;
  const int h = (i >> 5) & 15;
  const int bt = i >> 9;
  const int t = bt & 2047;
  const float inv = exp2f((float)d * -0.4152410118609203f);  // 10000^(-d/32)
  const float th = (float)t * inv;
  float s, c;
  sincosf(th, &s, &c);
  size_t base = (size_t)bt * 3072 + h * 64 + d;
#pragma unroll
  for (int half = 0; half < 2; ++half) {   // q then k
    const float x1 = b2f(qkv[base]);
    const float x2 = b2f(qkv[base + 32]);
    qkv[base]      = f2b(x1 * c - x2 * s);
    qkv[base + 32] = f2b(x2 * c + x1 * s);
    base += 1024;
  }
}

// ---------------------------------------------------------------------------
// V transpose: qkv (col offset 2048, stride 3072) -> VT (b,h,d,t), u16.
// block (32,8); grid (T/32, 2*B*NH)
// ---------------------------------------------------------------------------
__global__ void vtrans_k(const u16* __restrict__ qkv, u16* __restrict__ VT) {
  __shared__ u16 tl[32][34];
  const int t0 = blockIdx.x * 32;
  const int bh = blockIdx.y >> 1;
  const int d0 = (blockIdx.y & 1) * 32;
  const int b = bh >> 4, h = bh & 15;
  const int tx = threadIdx.x, ty = threadIdx.y;
  const u16* src = qkv + (size_t)(b * 2048 + t0) * 3072 + 2048 + h * 64 + d0;
#pragma unroll
  for (int i = 0; i < 4; ++i)
    tl[ty + 8 * i][tx] = src[(size_t)(ty + 8 * i) * 3072 + tx];
  __syncthreads();
  u16* dst = VT + ((size_t)bh * 64 + d0) * 2048 + t0;
#pragma unroll
  for (int i = 0; i < 4; ++i)
    dst[(size_t)(ty + 8 * i) * 2048 + tx] = tl[tx][ty + 8 * i];
}

// ---------------------------------------------------------------------------
// GEMM: C[M,N] = A[M,K] @ B[K,N], BT = B^T (N,K) row-major bf16; A row stride
// lda. 128x128 tile, BK=32, 256 thr, global_load_lds w16, mfma 16x16x32 bf16.
// EPI 0: bf16 store.  EPI 1: fp32 store of resid[off] + acc.
// ---------------------------------------------------------------------------
template <int EPI>
__global__ __launch_bounds__(256)
void gemm_bt(const u16* __restrict__ A, const u16* __restrict__ BT,
             void* __restrict__ Cout, const float* __restrict__ resid,
             int M, int N, int K, int lda) {
  __shared__ alignas(16) u16 As[128 * 32];
  __shared__ alignas(16) u16 Bs[128 * 32];
  const int tid = threadIdx.x;
  const int wave = tid >> 6, lane = tid & 63;
  const int wr = wave >> 1, wc = wave & 1;
  const int l15 = lane & 15, quad = lane >> 4;
  const int bm = blockIdx.x * 128, bn = blockIdx.y * 128;

  f32x4 acc[4][4];
#pragma unroll
  for (int i = 0; i < 4; ++i)
#pragma unroll
    for (int j = 0; j < 4; ++j) acc[i][j] = (f32x4){0.f, 0.f, 0.f, 0.f};

  const int srow = wave * 32 + (lane >> 2);
  const int scol = (lane & 3) * 8;
  const u16* gA0 = A + (size_t)(bm + srow) * lda + scol;
  const u16* gA1 = gA0 + (size_t)16 * lda;
  const u16* gB0 = BT + (size_t)(bn + srow) * K + scol;
  const u16* gB1 = gB0 + (size_t)16 * K;
  u16* lA0 = As + wave * 1024; u16* lA1 = lA0 + 512;
  u16* lB0 = Bs + wave * 1024; u16* lB1 = lB0 + 512;

  const u16* pa = As + (wr * 64 + l15) * 32 + quad * 8;
  const u16* pb = Bs + (wc * 64 + l15) * 32 + quad * 8;

  for (int kt = 0; kt < K; kt += 32) {
    gload_lds16(gA0 + kt, lA0);
    gload_lds16(gA1 + kt, lA1);
    gload_lds16(gB0 + kt, lB0);
    gload_lds16(gB1 + kt, lB1);
    __syncthreads();
    bf16x8 af[4], bfv[4];
#pragma unroll
    for (int i = 0; i < 4; ++i) af[i] = *(const bf16x8*)(pa + i * 512);
#pragma unroll
    for (int j = 0; j < 4; ++j) bfv[j] = *(const bf16x8*)(pb + j * 512);
#pragma unroll
    for (int i = 0; i < 4; ++i)
#pragma unroll
      for (int j = 0; j < 4; ++j)
        acc[i][j] = __builtin_amdgcn_mfma_f32_16x16x32_bf16(af[i], bfv[j], acc[i][j], 0, 0, 0);
    __syncthreads();
  }

#pragma unroll
  for (int i = 0; i < 4; ++i) {
    const int gr = bm + wr * 64 + i * 16 + quad * 4;
#pragma unroll
    for (int j = 0; j < 4; ++j) {
      const int gc = bn + wc * 64 + j * 16 + l15;
#pragma unroll
      for (int r = 0; r < 4; ++r) {
        const size_t off = (size_t)(gr + r) * N + gc;
        if (EPI == 0) {
          ((u16*)Cout)[off] = f2b(acc[i][j][r]);
        } else {
          ((float*)Cout)[off] = resid[off] + acc[i][j][r];
        }
      }
    }
  }
}

// ---------------------------------------------------------------------------
// Causal flash attention v4: fixed-bias softmax (no running max, no rescale
// -- exact since the constant cancels in O = sum(P V)/sum(P); scores are
// bounded |a|<~10 << 127 overflow margin), dual m-fragments (128 q-rows per
// block), two-barrier single-buffer K/V staging (round-2-proven), LPT.
// Q,K from qkv (stride 3072); V from VT (b,h,d,t). Row sums via ones-MFMA.
// ---------------------------------------------------------------------------
__global__ __launch_bounds__(256)
void attn_kernel(const u16* __restrict__ QKV, const u16* __restrict__ VT,
                 u16* __restrict__ O) {
  const int T = 2048, stQ = 3072;
  const int tid = threadIdx.x, wave = tid >> 6, lane = tid & 63;
  const int l15 = lane & 15, quad = lane >> 4;
  const int qt = (int)gridDim.x - 1 - (int)blockIdx.x;   // LPT: longest first
  const int qb0 = qt * 128;
  const int bh = blockIdx.y, b = bh >> 4, h = bh & 15;
  const float sc2 = 0.125f * 1.44269504088896f;   // scale * log2(e)
  const float M0 = 32.0f;                         // fixed softmax bias

  __shared__ alignas(16) u16 Kf[8 * 512];   // fragment-major [g=jj*2+hh][lane*8]
  __shared__ alignas(16) u16 Vf[8 * 512];
  __shared__ alignas(16) u16 Pl[4][2][16 * 72];

  const u16* Qb  = QKV + (size_t)b * T * stQ + h * 64;
  const u16* Kb  = Qb + 1024;
  const u16* VTb = VT + (size_t)bh * 64 * T;

  const int r0 = qb0 + wave * 16;   // frag0 wave rows
  const int r1 = r0 + 64;           // frag1 wave rows (always causally active)
  const u16* qp0 = Qb + (size_t)(r0 + l15) * stQ + quad * 8;
  const u16* qp1 = Qb + (size_t)(r1 + l15) * stQ + quad * 8;
  const bf16x8 qf00 = *(const bf16x8*)qp0;
  const bf16x8 qf01 = *(const bf16x8*)(qp0 + 32);
  const bf16x8 qf10 = *(const bf16x8*)qp1;
  const bf16x8 qf11 = *(const bf16x8*)(qp1 + 32);

  bf16x8 ones;
#pragma unroll
  for (int j = 0; j < 8; ++j) ones[j] = (short)0x3F80;   // bf16 1.0

  // staging sources (lane-permuted so LDS lands fragment-major)
  const u16* kS = Kb + (size_t)(wave * 16 + l15) * stQ + quad * 8;
  const u16* vS = VTb + (size_t)(wave * 16 + l15) * T + quad * 8;
  u16* kD0 = Kf + (wave * 2 + 0) * 512;  u16* kD1 = Kf + (wave * 2 + 1) * 512;
  u16* vD0 = Vf + (wave * 2 + 0) * 512;  u16* vD1 = Vf + (wave * 2 + 1) * 512;

  f32x4 o0[4], o1[4], sum0, sum1;
#pragma unroll
  for (int c = 0; c < 4; ++c) {
    o0[c] = (f32x4){0.f, 0.f, 0.f, 0.f};
    o1[c] = (f32x4){0.f, 0.f, 0.f, 0.f};
  }
  sum0 = (f32x4){0.f, 0.f, 0.f, 0.f};
  sum1 = (f32x4){0.f, 0.f, 0.f, 0.f};

  u16* pw0 = &Pl[wave][0][0];
  u16* pw1 = &Pl[wave][1][0];

  const int nkt = qt * 2 + 2;
  for (int kt = 0; kt < nkt; ++kt) {
    const int kb0 = kt * 64;
    gload_lds16(kS + (size_t)kb0 * stQ,      kD0);
    gload_lds16(kS + (size_t)kb0 * stQ + 32, kD1);
    gload_lds16(vS + kb0,                    vD0);
    gload_lds16(vS + kb0 + 32,               vD1);
    __syncthreads();

    bf16x8 kf[8];
#pragma unroll
    for (int g = 0; g < 8; ++g)
      kf[g] = *(const bf16x8*)(Kf + g * 512 + lane * 8);

    const bool act0 = (kb0 <= r0 + 15);   // wave-uniform causal tile skip

    // ---- frag1 (always active): S -> P(bf16, LDS) ----
    {
      f32x4 s[4];
#pragma unroll
      for (int jj = 0; jj < 4; ++jj) {
        s[jj] = (f32x4){0.f, 0.f, 0.f, 0.f};
        s[jj] = __builtin_amdgcn_mfma_f32_16x16x32_bf16(qf10, kf[jj * 2 + 0], s[jj], 0, 0, 0);
        s[jj] = __builtin_amdgcn_mfma_f32_16x16x32_bf16(qf11, kf[jj * 2 + 1], s[jj], 0, 0, 0);
      }
      if (kb0 + 63 > r1) {   // diagonal-crossing tile
#pragma unroll
        for (int jj = 0; jj < 4; ++jj)
#pragma unroll
          for (int r = 0; r < 4; ++r) {
            const bool msk = (kb0 + jj * 16 + l15) > (r1 + quad * 4 + r);
            const float a = msk ? -1e30f : (s[jj][r] * sc2 - M0);
            pw1[(quad * 4 + r) * 72 + jj * 16 + l15] = f2b(exp2f(a));
          }
      } else {
#pragma unroll
        for (int jj = 0; jj < 4; ++jj)
#pragma unroll
          for (int r = 0; r < 4; ++r)
            pw1[(quad * 4 + r) * 72 + jj * 16 + l15] =
                f2b(exp2f(s[jj][r] * sc2 - M0));
      }
    }
    // ---- frag0 (skippable) ----
    if (act0) {
      f32x4 s[4];
#pragma unroll
      for (int jj = 0; jj < 4; ++jj) {
        s[jj] = (f32x4){0.f, 0.f, 0.f, 0.f};
        s[jj] = __builtin_amdgcn_mfma_f32_16x16x32_bf16(qf00, kf[jj * 2 + 0], s[jj], 0, 0, 0);
        s[jj] = __builtin_amdgcn_mfma_f32_16x16x32_bf16(qf01, kf[jj * 2 + 1], s[jj], 0, 0, 0);
      }
      if (kb0 + 63 > r0) {
#pragma unroll
        for (int jj = 0; jj < 4; ++jj)
#pragma unroll
          for (int r = 0; r < 4; ++r) {
            const bool msk = (kb0 + jj * 16 + l15) > (r0 + quad * 4 + r);
            const float a = msk ? -1e30f : (s[jj][r] * sc2 - M0);
            pw0[(quad * 4 + r) * 72 + jj * 16 + l15] = f2b(exp2f(a));
          }
      } else {
#pragma unroll
        for (int jj = 0; jj < 4; ++jj)
#pragma unroll
          for (int r = 0; r < 4; ++r)
            pw0[(quad * 4 + r) * 72 + jj * 16 + l15] =
                f2b(exp2f(s[jj][r] * sc2 - M0));
      }
    }

    // ---- PV + row sums (no rescale needed: fixed bias) ----
    const bf16x8 pf10 = *(const bf16x8*)(pw1 + l15 * 72 + quad * 8);
    const bf16x8 pf11 = *(const bf16x8*)(pw1 + l15 * 72 + 32 + quad * 8);
#pragma unroll
    for (int c = 0; c < 4; ++c) {
      const bf16x8 v0 = *(const bf16x8*)(Vf + (c * 2 + 0) * 512 + lane * 8);
      const bf16x8 v1 = *(const bf16x8*)(Vf + (c * 2 + 1) * 512 + lane * 8);
      o1[c] = __builtin_amdgcn_mfma_f32_16x16x32_bf16(pf10, v0, o1[c], 0, 0, 0);
      o1[c] = __builtin_amdgcn_mfma_f32_16x16x32_bf16(pf11, v1, o1[c], 0, 0, 0);
    }
    sum1 = __builtin_amdgcn_mfma_f32_16x16x32_bf16(pf10, ones, sum1, 0, 0, 0);
    sum1 = __builtin_amdgcn_mfma_f32_16x16x32_bf16(pf11, ones, sum1, 0, 0, 0);
    if (act0) {
      const bf16x8 pf00 = *(const bf16x8*)(pw0 + l15 * 72 + quad * 8);
      const bf16x8 pf01 = *(const bf16x8*)(pw0 + l15 * 72 + 32 + quad * 8);
#pragma unroll
      for (int c = 0; c < 4; ++c) {
        const bf16x8 v0 = *(const bf16x8*)(Vf + (c * 2 + 0) * 512 + lane * 8);
        const bf16x8 v1 = *(const bf16x8*)(Vf + (c * 2 + 1) * 512 + lane * 8);
        o0[c] = __builtin_amdgcn_mfma_f32_16x16x32_bf16(pf00, v0, o0[c], 0, 0, 0);
        o0[c] = __builtin_amdgcn_mfma_f32_16x16x32_bf16(pf01, v1, o0[c], 0, 0, 0);
      }
      sum0 = __builtin_amdgcn_mfma_f32_16x16x32_bf16(pf00, ones, sum0, 0, 0, 0);
      sum0 = __builtin_amdgcn_mfma_f32_16x16x32_bf16(pf01, ones, sum0, 0, 0, 0);
    }
    __syncthreads();
  }

  float i0[4], i1[4];
#pragma unroll
  for (int r = 0; r < 4; ++r) { i0[r] = 1.f / sum0[r]; i1[r] = 1.f / sum1[r]; }
  u16* op0 = O + ((size_t)(b * T) + r0 + quad * 4) * 1024 + h * 64 + l15;
  u16* op1 = O + ((size_t)(b * T) + r1 + quad * 4) * 1024 + h * 64 + l15;
#pragma unroll
  for (int c = 0; c < 4; ++c)
#pragma unroll
    for (int r = 0; r < 4; ++r) {
      op0[(size_t)r * 1024 + c * 16] = f2b(o0[c][r] * i0[r]);
      op1[(size_t)r * 1024 + c * 16] = f2b(o1[c][r] * i1[r]);
    }
}

// ---------------------------------------------------------------------------
// SwiGLU gate, in-place on fused a13 (M x 8192): first half <- silu(a1)*a3.
// ---------------------------------------------------------------------------
__global__ __launch_bounds__(256) void gate_k(u16* __restrict__ a13) {
  const size_t i = (size_t)blockIdx.x * 256 + threadIdx.x;
  const size_t row = i >> 9, c8 = (i & 511) * 8;
  u16* p1v = a13 + row * 8192 + c8;
  const u16* p3v = p1v + 4096;
  uint4 u1 = *(uint4*)p1v;
  const uint4 u3 = *(const uint4*)p3v;
  u16* p1 = (u16*)&u1;
  const u16* p3 = (const u16*)&u3;
#pragma unroll
  for (int j = 0; j < 8; ++j) {
    const float a = b2f(p1[j]);
    const float g = b2f(p3[j]);
    const float s = a / (1.f + __expf(-a));
    p1[j] = f2b(s * g);
  }
  *(uint4*)p1v = u1;
}

// ---------------------------------------------------------------------------
extern "C" void kernel_launch(void* const* d_in, const int* in_sizes, int n_in,
                              void* d_out, int out_size, void* d_ws, size_t ws_size,
                              hipStream_t stream) {
  const float* x  = (const float*)d_in[0];
  const float* g1 = (const float*)d_in[2];
  const float* wq = (const float*)d_in[3];
  const float* wk = (const float*)d_in[4];
  const float* wv = (const float*)d_in[5];
  const float* wo = (const float*)d_in[6];
  const float* g2 = (const float*)d_in[7];
  const float* w1 = (const float*)d_in[8];
  const float* w2 = (const float*)d_in[9];
  const float* w3 = (const float*)d_in[10];
  float* out = (float*)d_out;

  const int T = 2048, NH = 16, B = 4;
  const int M = B * T;  // 8192
  const size_t MB = 1ull << 20;

  char* ws = (char*)d_ws;
  u16* hb    = (u16*)(ws);              // 16 MB
  u16* wqkvT = (u16*)(ws + 16 * MB);    // 6 MB (3072 x 1024)
  u16* woT   = (u16*)(ws + 22 * MB);    // 2 MB
  u16* w13T  = (u16*)(ws + 24 * MB);    // 16 MB (8192 x 1024: w1T then w3T)
  u16* w2T   = (u16*)(ws + 40 * MB);    // 8 MB (1024 x 4096)
  u16* qkv   = (u16*)(ws + 48 * MB);    // 48 MB (M x 3072)
  u16* VT    = (u16*)(ws + 96 * MB);    // 16 MB (b,h,d,t)
  u16* Ob    = (u16*)(ws + 112 * MB);   // 16 MB
  u16* a13   = (u16*)(ws + 48 * MB);    // 128 MB (M x 8192), overlays qkv/VT/Ob

  const dim3 tb(32, 8);
  transpose_f2b<<<dim3(32, 32),  tb, 0, stream>>>(wq, wqkvT,              1024, 1024);
  transpose_f2b<<<dim3(32, 32),  tb, 0, stream>>>(wk, wqkvT + 1024*1024,  1024, 1024);
  transpose_f2b<<<dim3(32, 32),  tb, 0, stream>>>(wv, wqkvT + 2048*1024,  1024, 1024);
  transpose_f2b<<<dim3(32, 32),  tb, 0, stream>>>(wo, woT, 1024, 1024);
  transpose_f2b<<<dim3(128, 32), tb, 0, stream>>>(w1, w13T,               1024, 4096);
  transpose_f2b<<<dim3(128, 32), tb, 0, stream>>>(w3, w13T + 4096*1024,   1024, 4096);
  transpose_f2b<<<dim3(32, 128), tb, 0, stream>>>(w2, w2T, 4096, 1024);

  rmsnorm_k<<<M, 256, 0, stream>>>(x, g1, hb);

  gemm_bt<0><<<dim3(64, 24), 256, 0, stream>>>(hb, wqkvT, qkv, nullptr, M, 3072, 1024, 1024);

  rope_k<<<16384, 256, 0, stream>>>(qkv);
  vtrans_k<<<dim3(64, 128), tb, 0, stream>>>(qkv, VT);

  attn_kernel<<<dim3(T / 128, B * NH), 256, 0, stream>>>(qkv, VT, Ob);

  gemm_bt<1><<<dim3(64, 8), 256, 0, stream>>>(Ob, woT, out, x, M, 1024, 1024, 1024);

  rmsnorm_k<<<M, 256, 0, stream>>>(out, g2, hb);

  gemm_bt<0><<<dim3(64, 64), 256, 0, stream>>>(hb, w13T, a13, nullptr, M, 8192, 1024, 1024);

  gate_k<<<16384, 256, 0, stream>>>(a13);

  gemm_bt<1><<<dim3(64, 8), 256, 0, stream>>>(a13, w2T, out, out, M, 1024, 4096, 8192);
}